// Round 11
// baseline (116.948 us; speedup 1.0000x reference)
//
#include <hip/hip_runtime.h>

#define DD 256
#define BB 8
#define SS 1024
#define XSTRIDE 264   // f16 elems per LDS row (528 B, 16B-aligned)

// ws layout per layer (bytes): Mtab 131072 | Ptab 131072 | Itab 262144 = 524288
#define LAYER_BYTES 524288
#define PTAB_OFF    131072
#define ITAB_OFF    262144
#define WS_NEEDED   (2 * LAYER_BYTES)

typedef _Float16 half8  __attribute__((ext_vector_type(8)));
typedef _Float16 half2t __attribute__((ext_vector_type(2)));
typedef __fp16   fp16x2 __attribute__((ext_vector_type(2)));
typedef __attribute__((ext_vector_type(4))) float float4v;

__device__ __forceinline__ half2t pkrtz(float a, float b) {
    union { fp16x2 f; half2t h; } cv;
    cv.f = __builtin_amdgcn_cvt_pkrtz(a, b);
    return cv.h;
}

// Fragment-ordered tables: gi = (kt*16 + wt)*64 + lane, lane = quad*16+l15,
// n = 16*wt + l15, j0 = kt*32 + quad*8:
//   Mtab[gi] = M[n][j0..j0+7] f16, Ptab[gi] = P[n][j0..j0+7] f16,
//   Itab[2gi..] = 1/(n*256 + j0 + e + 2) f32, e=0..7
__global__ void build_tabs(const float* __restrict__ M1, const float* __restrict__ P1,
                           const float* __restrict__ M2, const float* __restrict__ P2,
                           char* __restrict__ ws)
{
    int gid   = blockIdx.x * 256 + threadIdx.x;   // 0..16383
    int layer = gid >> 13;
    int gi    = gid & 8191;
    int idx   = gi >> 6;
    int lane  = gi & 63;
    int kt    = idx >> 4;
    int wt    = idx & 15;
    int l15   = lane & 15, quad = lane >> 4;
    int n     = 16 * wt + l15;
    int j0    = kt * 32 + quad * 8;

    const float* Msrc = layer ? M2 : M1;
    const float* Psrc = layer ? P2 : P1;

    union { half8 h; half2t h2[4]; } mh, ph;
    float iv[8];
    #pragma unroll
    for (int e = 0; e < 4; ++e) {
        float ma = Msrc[(size_t)n * DD + j0 + 2 * e];
        float mb = Msrc[(size_t)n * DD + j0 + 2 * e + 1];
        float pa = Psrc[(size_t)n * DD + j0 + 2 * e];
        float pb = Psrc[(size_t)n * DD + j0 + 2 * e + 1];
        mh.h2[e] = pkrtz(ma, mb);
        ph.h2[e] = pkrtz(pa, pb);
        iv[2 * e]     = 1.0f / (float)(n * DD + j0 + 2 * e + 2);
        iv[2 * e + 1] = 1.0f / (float)(n * DD + j0 + 2 * e + 3);
    }
    char* base = ws + (size_t)layer * LAYER_BYTES;
    ((half8*)base)[gi]              = mh.h;
    ((half8*)(base + PTAB_OFF))[gi] = ph.h;
    float4* it = (float4*)(base + ITAB_OFF);
    it[2 * gi]     = make_float4(iv[0], iv[1], iv[2], iv[3]);
    it[2 * gi + 1] = make_float4(iv[4], iv[5], iv[6], iv[7]);
}

// Block = 1024 threads (16 waves), s-pair (s0,s0+1) per block, grid 512.
// -> 2 blocks/CU x 16 waves = 32 waves/CU (8/SIMD): 2x round-10 TLP.
// Wave w owns exactly ONE n-tile (n = 16w + l15). A rows r = sl*8+b.
// Residual in registers. Tables give fully-coalesced hot-loop loads.
template<bool TABS>
__global__ __launch_bounds__(1024, 8)
void fused_hierddpm(const float* __restrict__ seq,
                    const float* __restrict__ M1, const float* __restrict__ P1,
                    const float* __restrict__ g1, const float* __restrict__ be1,
                    const float* __restrict__ M2, const float* __restrict__ P2,
                    const float* __restrict__ g2, const float* __restrict__ be2,
                    const char* __restrict__ ws,
                    float* __restrict__ out)
{
    __shared__ __align__(16) _Float16 xsb[16][XSTRIDE]; // input / layer-out, f16, A-layout
    __shared__ __align__(16) _Float16 xtb[16][XSTRIDE]; // LN'd xt, f16
    __shared__ float stats[16][16][2];

    const int tid  = threadIdx.x;
    const int w    = tid >> 6;          // wave id 0..15 == owned n-tile
    const int lane = tid & 63;
    const int l15  = lane & 15;
    const int quad = lane >> 4;
    const int s0   = blockIdx.x * 2;
    const float k0 = (float)s0, k1 = (float)(s0 + 1);
    const int col  = 16 * w + l15;      // this lane's output column

    // ---- stage x into xsb (f16, rows r = sl*8+b), coalesced float4 reads
    {
        const float4* seq4 = (const float4*)seq;
        int v  = tid;                   // float4 index 0..1023
        int sl = v >> 9;
        int rm = v & 511;
        int b  = rm >> 6, j4 = rm & 63;
        float4 x = seq4[((size_t)b * SS + s0 + sl) * 64 + j4];
        half2t* dst = (half2t*)&xsb[sl * 8 + b][4 * j4];
        dst[0] = pkrtz(x.x, x.y);
        dst[1] = pkrtz(x.z, x.w);
    }

    // ---- residual in registers: res[reg] for (sl=quad>>1, b=(quad*4+reg)&7, col)
    float res[4];
    {
        const int sl = quad >> 1;
        #pragma unroll
        for (int reg = 0; reg < 4; ++reg) {
            int b = (quad * 4 + reg) & 7;
            res[reg] = seq[((size_t)b * SS + s0 + sl) * DD + col];
        }
    }
    __syncthreads();

    #pragma unroll 1
    for (int layer = 0; layer < 2; ++layer) {
        const float* M  = layer ? M2  : M1;
        const float* P  = layer ? P2  : P1;
        const float* g  = layer ? g2  : g1;
        const float* be = layer ? be2 : be1;
        const char*  lbase = ws + (size_t)layer * LAYER_BYTES;
        const half8*  Mtab = (const half8*)lbase;
        const half8*  Ptab = (const half8*)(lbase + PTAB_OFF);
        const float4* Itab = (const float4*)(lbase + ITAB_OFF);

        // ======== phase A: xt = x @ M^T (f16 MFMA); wave owns n-tile w
        float4v acc1 = (float4v){0.f, 0.f, 0.f, 0.f};

        #pragma unroll 2
        for (int kt = 0; kt < 8; ++kt) {
            half8 a = *(const half8*)&xsb[l15][kt * 32 + quad * 8];
            half8 bfrag;
            if (TABS) {
                bfrag = Mtab[(kt * 16 + w) * 64 + lane];
            } else {
                int n = 16 * w + l15;
                const float4* Mr = (const float4*)M +
                    ((size_t)n * 64 + kt * 8 + quad * 2);
                float4 m0 = Mr[0], m1 = Mr[1];
                union { half8 h; half2t h2[4]; } bb;
                bb.h2[0] = pkrtz(m0.x, m0.y);
                bb.h2[1] = pkrtz(m0.z, m0.w);
                bb.h2[2] = pkrtz(m1.x, m1.y);
                bb.h2[3] = pkrtz(m1.z, m1.w);
                bfrag = bb.h;
            }
            acc1 = __builtin_amdgcn_mfma_f32_16x16x32_f16(a, bfrag, acc1, 0, 0, 0);
        }

        // ======== LayerNorm in C-register layout (row m = quad*4+reg)
        {
            #pragma unroll
            for (int reg = 0; reg < 4; ++reg) {
                float sm = acc1[reg];
                float sq = acc1[reg] * acc1[reg];
                #pragma unroll
                for (int off = 1; off < 16; off <<= 1) {
                    sm += __shfl_xor(sm, off, 64);
                    sq += __shfl_xor(sq, off, 64);
                }
                if (l15 == 0) {
                    stats[w][quad * 4 + reg][0] = sm;
                    stats[w][quad * 4 + reg][1] = sq;
                }
            }
        }
        __syncthreads();
        {
            float mu[4], rs[4];
            #pragma unroll
            for (int reg = 0; reg < 4; ++reg) {
                int m = quad * 4 + reg;
                float sm = 0.f, sq = 0.f;
                #pragma unroll
                for (int ww = 0; ww < 16; ++ww) {
                    sm += stats[ww][m][0];
                    sq += stats[ww][m][1];
                }
                float mm = sm * (1.f / DD);
                mu[reg] = mm;
                rs[reg] = rsqrtf(sq * (1.f / DD) - mm * mm + 1e-5f);
            }
            float gv = g[col], bv = be[col];
            #pragma unroll
            for (int reg = 0; reg < 4; ++reg) {
                float v = fmaf((acc1[reg] - mu[reg]) * rs[reg], gv, bv);
                xtb[quad * 4 + reg][col] = (_Float16)v;
            }
        }
        __syncthreads();   // xtb ready for phase B

        // ======== phase B: Nk = xt @ W_s^T; W = P * cos generated in regs (f16)
        float4v accS[2];
        accS[0] = (float4v){0.f, 0.f, 0.f, 0.f};
        accS[1] = (float4v){0.f, 0.f, 0.f, 0.f};

        #pragma unroll 2
        for (int kt = 0; kt < 8; ++kt) {
            half8 a = *(const half8*)&xtb[l15][kt * 32 + quad * 8];
            union { half8 h; half2t h2[4]; } pv;
            float iv[8];
            if (TABS) {
                int gi = (kt * 16 + w) * 64 + lane;
                pv.h = Ptab[gi];
                float4 i0 = Itab[2 * gi], i1 = Itab[2 * gi + 1];
                iv[0] = i0.x; iv[1] = i0.y; iv[2] = i0.z; iv[3] = i0.w;
                iv[4] = i1.x; iv[5] = i1.y; iv[6] = i1.z; iv[7] = i1.w;
            } else {
                int n = 16 * w + l15;
                const float4* Pr = (const float4*)P +
                    ((size_t)n * 64 + kt * 8 + quad * 2);
                float4 p0 = Pr[0], p1 = Pr[1];
                pv.h2[0] = pkrtz(p0.x, p0.y);
                pv.h2[1] = pkrtz(p0.z, p0.w);
                pv.h2[2] = pkrtz(p1.x, p1.y);
                pv.h2[3] = pkrtz(p1.z, p1.w);
                float pbase = (float)(n * DD + kt * 32 + quad * 8 + 2);
                #pragma unroll
                for (int e = 0; e < 8; ++e)
                    iv[e] = __builtin_amdgcn_rcpf(pbase + (float)e);
            }
            union { half8 h; half2t h2[4]; } b0, b1;
            #pragma unroll
            for (int e = 0; e < 4; ++e) {
                float ia = iv[2 * e], ib = iv[2 * e + 1];
                half2t c0 = pkrtz(
                    __builtin_amdgcn_cosf(__builtin_amdgcn_fractf(k0 * ia)),
                    __builtin_amdgcn_cosf(__builtin_amdgcn_fractf(k0 * ib)));
                half2t c1 = pkrtz(
                    __builtin_amdgcn_cosf(__builtin_amdgcn_fractf(k1 * ia)),
                    __builtin_amdgcn_cosf(__builtin_amdgcn_fractf(k1 * ib)));
                b0.h2[e] = pv.h2[e] * c0;   // v_pk_mul_f16
                b1.h2[e] = pv.h2[e] * c1;
            }
            accS[0] = __builtin_amdgcn_mfma_f32_16x16x32_f16(a, b0.h, accS[0], 0, 0, 0);
            accS[1] = __builtin_amdgcn_mfma_f32_16x16x32_f16(a, b1.h, accS[1], 0, 0, 0);
        }

        // ======== epilogue: pick valid s-half per quad, add register residual
        {
            float4v av = (quad < 2) ? accS[0] : accS[1];
            int sl = quad >> 1;
            #pragma unroll
            for (int reg = 0; reg < 4; ++reg) {
                int m = quad * 4 + reg;
                int b = m & 7;
                float val = av[reg] + res[reg];
                if (layer == 0) {
                    res[reg]    = val;             // next layer's residual
                    xsb[m][col] = (_Float16)val;   // next layer's A-matrix
                } else {
                    out[((size_t)b * SS + s0 + sl) * DD + col] = val;
                }
            }
        }
        if (layer == 0) __syncthreads();
    }
}

extern "C" void kernel_launch(void* const* d_in, const int* in_sizes, int n_in,
                              void* d_out, int out_size, void* d_ws, size_t ws_size,
                              hipStream_t stream)
{
    const float* seq = (const float*)d_in[0];
    const float* M1  = (const float*)d_in[1];
    const float* P1  = (const float*)d_in[2];
    const float* g1  = (const float*)d_in[3];
    const float* b1  = (const float*)d_in[4];
    const float* M2  = (const float*)d_in[5];
    const float* P2  = (const float*)d_in[6];
    const float* g2  = (const float*)d_in[7];
    const float* b2  = (const float*)d_in[8];
    float* out = (float*)d_out;

    if (ws_size >= WS_NEEDED) {
        build_tabs<<<64, 256, 0, stream>>>(M1, P1, M2, P2, (char*)d_ws);
        fused_hierddpm<true><<<SS / 2, 1024, 0, stream>>>(
            seq, M1, P1, g1, b1, M2, P2, g2, b2, (const char*)d_ws, out);
    } else {
        fused_hierddpm<false><<<SS / 2, 1024, 0, stream>>>(
            seq, M1, P1, g1, b1, M2, P2, g2, b2, nullptr, out);
    }
}